// Round 6
// baseline (253.724 us; speedup 1.0000x reference)
//
#include <hip/hip_runtime.h>
#include <math.h>

#define C_DIM 2048
#define E_DIM 64
#define BT    32       // tokens per block
#define NW    4        // waves per block = K-split factor

typedef _Float16 v8hf  __attribute__((ext_vector_type(8)));
typedef float    f32x4 __attribute__((ext_vector_type(4)));

#define SCALE      64.0f
#define INV_SCALE2 (1.0f/4096.0f)

// ---------------- K0: w -> fragment-ordered f16 (hi,lo), scaled x64 ----------------
// For K32-step q (0..63), expert-group ni (0..3): 2 KB block = hi(1 KB) + lo(1 KB),
// each 64 lanes x 16 B. Lane l holds w[16ni+(l&15)][32q+(l>>4)*8 .. +8].
__launch_bounds__(256)
__global__ void k_wsplit(const float* __restrict__ w, _Float16* __restrict__ wfrag)
{
    int t  = blockIdx.x * 256 + threadIdx.x;   // 0..16383
    int l  = t & 63;
    int ni = (t >> 6) & 3;
    int q  = t >> 8;
    int e  = 16 * ni + (l & 15);
    int k0 = 32 * q + (l >> 4) * 8;
    const float* src = w + (size_t)e * C_DIM + k0;
    float4 a = *(const float4*)(src);
    float4 b = *(const float4*)(src + 4);
    float s[8] = {a.x, a.y, a.z, a.w, b.x, b.y, b.z, b.w};
    v8hf hv, lv;
#pragma unroll
    for (int j = 0; j < 8; ++j) {
        float sc = s[j] * SCALE;
        _Float16 h = (_Float16)sc;          // RNE
        hv[j] = h;
        lv[j] = (_Float16)(sc - (float)h);  // Sterbenz-exact residual, then RNE
    }
    size_t fo = (size_t)(q * 4 + ni) * 1024;   // f16 units: 1024 f16 = 2 KB per (q,ni)
    *(v8hf*)(wfrag + fo + l * 8)       = hv;
    *(v8hf*)(wfrag + fo + 512 + l * 8) = lv;
}

// ---------------- K1: barrier-free MFMA logits + top-2 + histogram ----------------
// Block: 32 tokens x 64 experts, 4 waves = 4-way K-split (wave wk owns K32-steps
// q = 4c+wk). NO LDS and NO barriers in the K-loop: each wave loads its A-frags
// directly from global x in fragment layout (lane l: 32 B of row 16mi+(l&15) at
// k = 128c+32wk+8*(l>>4)), converts f32 -> f16 hi/lo in registers, and streams.
// B-frags are coalesced 16 B/lane reads of the fragment-ordered wfrag (L2/L3).
// Register double-buffer one step ahead; 16 fully-unrolled steps.
// Epilogue: deterministic 4-round LDS reduction over wk, then per-token top-2.
__launch_bounds__(256)
__global__ void k_logits_top2(const float* __restrict__ x, const _Float16* __restrict__ wfrag,
                              unsigned char* __restrict__ idx0, unsigned char* __restrict__ idx1,
                              float* __restrict__ dlt, unsigned short* __restrict__ gcounts,
                              int nblk)
{
    __shared__ float lgs[BT * E_DIM];     // 8 KB
    __shared__ int   cnt[128];

    const int tid  = threadIdx.x;
    const int lane = tid & 63;
    const int wk   = tid >> 6;            // 0..3 : K-split index
    const int ln15 = lane & 15;
    const int g    = lane >> 4;           // k-group 0..3
    const int t0   = blockIdx.x * BT;

    if (tid < 128) cnt[tid] = 0;

    f32x4 acc[2][4];
#pragma unroll
    for (int mi = 0; mi < 2; ++mi)
#pragma unroll
        for (int ni = 0; ni < 4; ++ni) acc[mi][ni] = (f32x4)0.0f;

    // per-lane base addresses (step stride: 128 floats in x, 32 KB in wfrag)
    const float* xb = x + (size_t)(t0 + ln15) * C_DIM + 32 * wk + 8 * g;
    const char*  wb = (const char*)wfrag + ((size_t)wk << 13) + (lane << 4);

    float4 axf[2][2][2];                  // [buf][mi][half] raw f32 A data
    v8hf   bhf[2][4], blf[2][4];          // [buf][ni]

#define LOADSTEP(c, s)                                                          \
    {                                                                           \
        _Pragma("unroll")                                                       \
        for (int mi = 0; mi < 2; ++mi) {                                        \
            const float* p = xb + (size_t)(16 * mi) * C_DIM + (c) * 128;        \
            axf[s][mi][0] = *(const float4*)(p);                                \
            axf[s][mi][1] = *(const float4*)(p + 4);                            \
        }                                                                       \
        const char* wp = wb + (size_t)(c) * 32768;                              \
        _Pragma("unroll")                                                       \
        for (int ni = 0; ni < 4; ++ni) {                                        \
            bhf[s][ni] = *(const v8hf*)(wp + ni * 2048);                        \
            blf[s][ni] = *(const v8hf*)(wp + ni * 2048 + 1024);                 \
        }                                                                       \
    }

#define DOSTEP(s)                                                               \
    {                                                                           \
        v8hf ah[2], al[2];                                                      \
        _Pragma("unroll")                                                       \
        for (int mi = 0; mi < 2; ++mi) {                                        \
            float sv[8] = {axf[s][mi][0].x, axf[s][mi][0].y, axf[s][mi][0].z,   \
                           axf[s][mi][0].w, axf[s][mi][1].x, axf[s][mi][1].y,   \
                           axf[s][mi][1].z, axf[s][mi][1].w};                   \
            _Pragma("unroll")                                                   \
            for (int j = 0; j < 8; ++j) {                                       \
                float sc = sv[j] * SCALE;                                       \
                _Float16 h = (_Float16)sc;                                      \
                ah[mi][j] = h;                                                  \
                al[mi][j] = (_Float16)(sc - (float)h);                          \
            }                                                                   \
        }                                                                       \
        _Pragma("unroll")                                                       \
        for (int ni = 0; ni < 4; ++ni)                                          \
            _Pragma("unroll")                                                   \
            for (int mi = 0; mi < 2; ++mi) {                                    \
                acc[mi][ni] = __builtin_amdgcn_mfma_f32_16x16x32_f16(ah[mi], bhf[s][ni], acc[mi][ni], 0, 0, 0); \
                acc[mi][ni] = __builtin_amdgcn_mfma_f32_16x16x32_f16(ah[mi], blf[s][ni], acc[mi][ni], 0, 0, 0); \
                acc[mi][ni] = __builtin_amdgcn_mfma_f32_16x16x32_f16(al[mi], bhf[s][ni], acc[mi][ni], 0, 0, 0); \
            }                                                                   \
    }

    LOADSTEP(0, 0);
#pragma unroll
    for (int c = 0; c < 16; ++c) {
        const int cur = c & 1;
        if (c < 15) LOADSTEP(c + 1, cur ^ 1);   // prefetch next step (x: HBM/L3, B: L2)
        DOSTEP(cur);
    }

    // ---- deterministic K-split reduction into lgs[32][64] ----
#pragma unroll
    for (int w = 0; w < NW; ++w) {
        if (w > 0) __syncthreads();
        if (wk == w) {
#pragma unroll
            for (int mi = 0; mi < 2; ++mi)
#pragma unroll
                for (int ni = 0; ni < 4; ++ni)
#pragma unroll
                    for (int gg = 0; gg < 4; ++gg) {
                        int row = 16 * mi + (g << 2) + gg;    // C/D: row=(l>>4)*4+reg
                        int e   = 16 * ni + ln15;             // col=l&15
                        float vv = acc[mi][ni][gg] * INV_SCALE2;
                        if (w == 0) lgs[row * 64 + e]  = vv;
                        else        lgs[row * 64 + e] += vv;
                    }
        }
    }
    __syncthreads();

    // ---- per-token top-2 (lane == expert), lower index wins ties ----
#pragma unroll
    for (int t = 0; t < 8; ++t) {
        int rowl = (wk << 3) + t;
        float v = lgs[rowl * 64 + lane];
        float vv = v; int ix = lane;
#pragma unroll
        for (int off = 32; off > 0; off >>= 1) {
            float ov = __shfl_down(vv, off, 64);
            int   oi = __shfl_down(ix, off, 64);
            if (ov > vv || (ov == vv && oi < ix)) { vv = ov; ix = oi; }
        }
        int   i1 = __shfl(ix, 0, 64);
        float v1 = __shfl(vv, 0, 64);

        vv = (lane == i1) ? -3.0e38f : v; ix = lane;
#pragma unroll
        for (int off = 32; off > 0; off >>= 1) {
            float ov = __shfl_down(vv, off, 64);
            int   oi = __shfl_down(ix, off, 64);
            if (ov > vv || (ov == vv && oi < ix)) { vv = ov; ix = oi; }
        }
        int   i2 = __shfl(ix, 0, 64);
        float v2 = __shfl(vv, 0, 64);

        if (lane == 0) {
            int n = t0 + rowl;
            idx0[n] = (unsigned char)i1;
            idx1[n] = (unsigned char)i2;
            dlt[n]  = v2 - v1;             // probs recomputed in k_rank_out
            atomicAdd(&cnt[i1], 1);
            atomicAdd(&cnt[64 + i2], 1);
        }
    }

    __syncthreads();
    if (tid < 128) {
        int e = tid & 63, k = tid >> 6;    // segment s = k*nblk + block (k-major = rank order)
        gcounts[(size_t)e * (2 * nblk) + k * nblk + blockIdx.x] = (unsigned short)cnt[tid];
    }
}

// ---------------- K2: in-place exclusive prefix over segments, per expert ----------------
__launch_bounds__(64)
__global__ void k_scan2(unsigned short* __restrict__ g, int S)
{
    const int e = blockIdx.x, lane = threadIdx.x;
    unsigned short* row = g + (size_t)e * S;
    int vals[16];                          // S = 1024 -> 16 rounds of 64
    const int R = S >> 6;
#pragma unroll
    for (int r = 0; r < 16; ++r) if (r < R) vals[r] = row[(r << 6) + lane];
    int running = 0;
#pragma unroll
    for (int r = 0; r < 16; ++r) {
        if (r >= R) break;
        int v = vals[r], s = v;
#pragma unroll
        for (int off = 1; off < 64; off <<= 1) {
            int t = __shfl_up(s, off, 64);
            if (lane >= off) s += t;
        }
        row[(r << 6) + lane] = (unsigned short)(s - v + running);   // exclusive + carry
        running += __shfl(s, 63, 64);
    }
}

// ---------------- K3: ranks (1 prefix load + ballot) + mask + tail ----------------
__launch_bounds__(128)
__global__ void k_rank_out(const unsigned char* __restrict__ idx0, const unsigned char* __restrict__ idx1,
                           const unsigned short* __restrict__ gpre, const float* __restrict__ dlt,
                           float* __restrict__ out, int N, int cap, int nblk)
{
    const int b = blockIdx.x, tid = threadIdx.x;
    const int lane = tid & 63, kk = tid >> 6;   // wave 0: k=0, wave 1: k=1
    const int t0 = b * BT;
    __shared__ int sm_ix[2][BT], sm_rk[2][BT];

    int v = -1, base = 0;
    if (lane < BT) {
        v = (kk ? idx1 : idx0)[t0 + lane];
        base = gpre[(size_t)v * (2 * nblk) + kk * nblk + b];   // exclusive prefix of earlier segments
    }
    const unsigned long long ltm = (1ull << lane) - 1ull;
    int pre = 0;
    for (int e = 0; e < 64; ++e) {
        unsigned long long bb = __ballot(v == e);
        if (v == e) pre = __popcll(bb & ltm);
    }
    if (lane < BT) { sm_ix[kk][lane] = v; sm_rk[kk][lane] = base + pre; }
    __syncthreads();

    // one-hot capacity mask: 32 tokens x 128 floats = 1024 float4, 8/thread
#pragma unroll
    for (int rep = 0; rep < 8; ++rep) {
        int f   = tid + 128 * rep;
        int n2  = f >> 5;
        int rem = (f & 31) * 4;
        int kq  = rem >> 6;
        int e0  = rem & 63;
        int ix  = sm_ix[kq][n2];
        int rr  = sm_rk[kq][n2];
        float val = (rr < cap) ? 1.0f : 0.0f;
        float4 o = make_float4(0.f, 0.f, 0.f, 0.f);
        int d = ix - e0;
        if (d >= 0 && d < 4) ((float*)&o)[d] = val;
        *(float4*)(out + (size_t)(t0 + n2) * 128 + rem) = o;
    }

    // tail: probs_masked / indices / final_rank / capacity
    size_t B = (size_t)2 * N * E_DIM;
    if (tid < 2 * BT) {
        int n2 = tid >> 1, kq = tid & 1;
        int n  = t0 + n2;
        int gi = 2 * n + kq;
        int ix = sm_ix[kq][n2];
        int rr = sm_rk[kq][n2];
        float d  = dlt[n];                  // v2 - v1 (<= 0)
        float e1 = expf(d);
        float inv = 1.0f / (1.0f + e1);     // = jax f32 softmax([v1,v2])
        float p  = kq ? (e1 * inv) : inv;
        bool keep = rr < cap;
        out[B + gi]         = keep ? p : 0.0f;
        out[B + 2 * N + gi] = (float)ix;
        out[B + 4 * N + gi] = (float)rr;
    }
    if (b == 0 && tid == 0) out[B + 6 * N] = (float)cap;
}

extern "C" void kernel_launch(void* const* d_in, const int* in_sizes, int n_in,
                              void* d_out, int out_size, void* d_ws, size_t ws_size,
                              hipStream_t stream)
{
    const float* x  = (const float*)d_in[0];
    const float* wg = (const float*)d_in[1];
    const int N = in_sizes[0] / C_DIM;   // 16384 tokens
    const int nblk = N / BT;             // 512

    // workspace: idx0[N]u8 idx1[N]u8 dlt[N]f32 gcounts[64][2*nblk]u16 wfrag[256K f16] = 736 KB
    char* ws = (char*)d_ws;
    unsigned char*  idx0    = (unsigned char*)ws;
    unsigned char*  idx1    = idx0 + N;
    float*          dlt     = (float*)(idx1 + N);
    unsigned short* gcounts = (unsigned short*)(dlt + N);
    _Float16*       wfrag   = (_Float16*)(gcounts + (size_t)64 * 2 * nblk);

    float* out = (float*)d_out;

    int cap = (int)((long long)2 * 2 * N / E_DIM);   // TOP_K * EVAL_CAPACITY * N / E
    if (cap < 4) cap = 4;

    k_wsplit<<<64, 256, 0, stream>>>(wg, wfrag);
    k_logits_top2<<<nblk, 256, 0, stream>>>(x, wfrag, idx0, idx1, dlt, gcounts, nblk);
    k_scan2<<<E_DIM, 64, 0, stream>>>(gcounts, 2 * nblk);
    k_rank_out<<<nblk, 128, 0, stream>>>(idx0, idx1, gcounts, dlt, out, N, cap, nblk);
}

// Round 7
// 237.673 us; speedup vs baseline: 1.0675x; 1.0675x over previous
//
#include <hip/hip_runtime.h>
#include <math.h>

#define C_DIM 2048
#define E_DIM 64
#define BT    32       // tokens per block
#define NW    4        // waves per block = K-split factor

typedef _Float16 v8hf  __attribute__((ext_vector_type(8)));
typedef float    f32x4 __attribute__((ext_vector_type(4)));

#define SCALE      64.0f
#define INV_SCALE2 (1.0f/4096.0f)

typedef __attribute__((address_space(3))) char lds_char;

__device__ __forceinline__ void gl16(const void* g, lds_char* l)
{
    __builtin_amdgcn_global_load_lds((const __attribute__((address_space(1))) void*)g,
                                     (__attribute__((address_space(3))) void*)l, 16, 0, 0);
}

// ---------------- K0: w -> fragment-ordered f16 (hi,lo), scaled x64 ----------------
// For K32-step q (0..63), expert-group ni (0..3): 2 KB block = hi(1 KB) + lo(1 KB),
// each 64 lanes x 16 B. Lane l holds w[16ni+(l&15)][32q+(l>>4)*8 .. +8].
__launch_bounds__(256)
__global__ void k_wsplit(const float* __restrict__ w, _Float16* __restrict__ wfrag)
{
    int t  = blockIdx.x * 256 + threadIdx.x;   // 0..16383
    int l  = t & 63;
    int ni = (t >> 6) & 3;
    int q  = t >> 8;
    int e  = 16 * ni + (l & 15);
    int k0 = 32 * q + (l >> 4) * 8;
    const float* src = w + (size_t)e * C_DIM + k0;
    float4 a = *(const float4*)(src);
    float4 b = *(const float4*)(src + 4);
    float s[8] = {a.x, a.y, a.z, a.w, b.x, b.y, b.z, b.w};
    v8hf hv, lv;
#pragma unroll
    for (int j = 0; j < 8; ++j) {
        float sc = s[j] * SCALE;
        _Float16 h = (_Float16)sc;          // RNE
        hv[j] = h;
        lv[j] = (_Float16)(sc - (float)h);  // Sterbenz-exact residual, then RNE
    }
    size_t fo = (size_t)(q * 4 + ni) * 1024;   // f16 units: 1024 f16 = 2 KB per (q,ni)
    *(v8hf*)(wfrag + fo + l * 8)       = hv;
    *(v8hf*)(wfrag + fo + 512 + l * 8) = lv;
}

// ---------------- K1: deep-async MFMA logits + top-2 + histogram ----------------
// Block: 32 tokens x 64 experts, 4 waves = 4-way K-split (wave wk owns K32-step
// q = 4c+wk of chunk c). x flows HBM -> LDS via global_load_lds into a 4-deep
// per-wave ring of fragment-plane slices (1 KB planes, lane-linear dest == A-frag
// order; per-lane scatter on the GLOBAL side). 3 chunks of x stay in flight
// continuously (counted vmcnt(28), never drained in-loop) -> HBM saturated by
// Little's law. B frags are register-double-buffered coalesced L2 loads of the
// fragment-ordered wfrag. ZERO barriers in the K-loop (all ring slices are
// wave-private). f32->f16 hi/lo split happens on the LDS-read side; 3 MFMA
// products into one fp32 acc (same numerics as prior passing rounds).
__launch_bounds__(256)
__global__ void k_logits_top2(const float* __restrict__ x, const _Float16* __restrict__ wfrag,
                              unsigned char* __restrict__ idx0, unsigned char* __restrict__ idx1,
                              float* __restrict__ dlt, unsigned short* __restrict__ gcounts,
                              int nblk)
{
    __shared__ alignas(16) char smem[65536];   // ring: [slot r 0..3][wave][mi][plane] 1 KB planes

    const int tid  = threadIdx.x;
    const int lane = tid & 63;
    const int wk   = tid >> 6;            // 0..3 : K-split index
    const int ln15 = lane & 15;
    const int g4   = lane >> 4;
    const int t0   = blockIdx.x * BT;

    f32x4 acc[2][4];
#pragma unroll
    for (int mi = 0; mi < 2; ++mi)
#pragma unroll
        for (int ni = 0; ni < 4; ++ni) acc[mi][ni] = (f32x4)0.0f;

    v8hf bh[2][4], bl[2][4];              // B double-buffer (literal indices only)
    v8hf ah[2], al[2];

    // per-lane global base for A-fragments: row t0+ln15, k-offset 32wk + 8*g4
    const float* xlane = x + (size_t)(t0 + ln15) * C_DIM + 32 * wk + 8 * g4;
    const char*  wlane = (const char*)wfrag + (lane << 4);
    lds_char* s3    = (lds_char*)smem;
    lds_char* sbase = s3 + wk * 4096;     // + (c&3)*16384 + mi*2048 + p*1024

#define ISSUE_X(cc)                                                             \
    do {                                                                        \
        lds_char*    d  = sbase + (((cc) & 3) * 16384);                         \
        const float* gp = xlane + (cc) * 128;                                   \
        gl16(gp,                  d);                                           \
        gl16(gp + 4,              d + 1024);                                    \
        gl16(gp + 16 * C_DIM,     d + 2048);                                    \
        gl16(gp + 16 * C_DIM + 4, d + 3072);                                    \
    } while (0)

#define ISSUE_B(cc, s)                                                          \
    do {                                                                        \
        const char* wp = wlane + ((size_t)(4 * (cc) + wk) << 13);               \
        bh[s][0] = *(const v8hf*)(wp);          bl[s][0] = *(const v8hf*)(wp + 1024); \
        bh[s][1] = *(const v8hf*)(wp + 2048);   bl[s][1] = *(const v8hf*)(wp + 3072); \
        bh[s][2] = *(const v8hf*)(wp + 4096);   bl[s][2] = *(const v8hf*)(wp + 5120); \
        bh[s][3] = *(const v8hf*)(wp + 6144);   bl[s][3] = *(const v8hf*)(wp + 7168); \
    } while (0)

#define CVT(mi, lo, hi)                                                         \
    do {                                                                        \
        _Pragma("unroll")                                                       \
        for (int j = 0; j < 4; ++j) {                                           \
            float sc0 = (lo)[j] * SCALE;                                        \
            _Float16 h0 = (_Float16)sc0;                                        \
            ah[mi][j] = h0; al[mi][j] = (_Float16)(sc0 - (float)h0);            \
            float sc1 = (hi)[j] * SCALE;                                        \
            _Float16 h1 = (_Float16)sc1;                                        \
            ah[mi][j + 4] = h1; al[mi][j + 4] = (_Float16)(sc1 - (float)h1);    \
        }                                                                       \
    } while (0)

#define COMPUTE(cc, s)                                                          \
    do {                                                                        \
        const char* rb = smem + wk * 4096 + (((cc) & 3) * 16384) + lane * 16;   \
        f32x4 lo0 = *(const f32x4*)(rb);                                        \
        f32x4 hi0 = *(const f32x4*)(rb + 1024);                                 \
        f32x4 lo1 = *(const f32x4*)(rb + 2048);                                 \
        f32x4 hi1 = *(const f32x4*)(rb + 3072);                                 \
        CVT(0, lo0, hi0);                                                       \
        CVT(1, lo1, hi1);                                                       \
        _Pragma("unroll")                                                       \
        for (int ni = 0; ni < 4; ++ni) {                                        \
            acc[0][ni] = __builtin_amdgcn_mfma_f32_16x16x32_f16(ah[0], bh[s][ni], acc[0][ni], 0, 0, 0); \
            acc[0][ni] = __builtin_amdgcn_mfma_f32_16x16x32_f16(ah[0], bl[s][ni], acc[0][ni], 0, 0, 0); \
            acc[0][ni] = __builtin_amdgcn_mfma_f32_16x16x32_f16(al[0], bh[s][ni], acc[0][ni], 0, 0, 0); \
            acc[1][ni] = __builtin_amdgcn_mfma_f32_16x16x32_f16(ah[1], bh[s][ni], acc[1][ni], 0, 0, 0); \
            acc[1][ni] = __builtin_amdgcn_mfma_f32_16x16x32_f16(ah[1], bl[s][ni], acc[1][ni], 0, 0, 0); \
            acc[1][ni] = __builtin_amdgcn_mfma_f32_16x16x32_f16(al[1], bh[s][ni], acc[1][ni], 0, 0, 0); \
        }                                                                       \
    } while (0)

// steady state before the wait: outstanding = x(c),x(c+1),x(c+2),x(c+3),B(c),B(c+1)
// = 16 + 16 = 32 VMEM ops; the 28 newer than x(c) stay in flight. Wrap-issued
// tails ((c+3)&15 / (c+1)&15) keep the count uniform for all 16 chunks (the few
// redundant reloads of early chunks are harmless: same bytes, same slots).
#define CHUNK(c, CUR, NXT)                                                      \
    ISSUE_X(((c) + 3) & 15);                                                    \
    ISSUE_B(((c) + 1) & 15, NXT);                                               \
    asm volatile("s_waitcnt vmcnt(28)" ::: "memory");                           \
    COMPUTE(c, CUR);

    // prologue: 3 chunks of x in flight + B(0)
    ISSUE_X(0); ISSUE_X(1); ISSUE_X(2);
    ISSUE_B(0, 0);

    CHUNK(0, 0, 1)  CHUNK(1, 1, 0)  CHUNK(2, 0, 1)  CHUNK(3, 1, 0)
    CHUNK(4, 0, 1)  CHUNK(5, 1, 0)  CHUNK(6, 0, 1)  CHUNK(7, 1, 0)
    CHUNK(8, 0, 1)  CHUNK(9, 1, 0)  CHUNK(10, 0, 1) CHUNK(11, 1, 0)
    CHUNK(12, 0, 1) CHUNK(13, 1, 0) CHUNK(14, 0, 1) CHUNK(15, 1, 0)

    asm volatile("s_waitcnt vmcnt(0)" ::: "memory");
    __syncthreads();                       // ring dead; smem reused below

    // ---- deterministic K-split reduction into lgs[32][64] ----
    float* lgs = (float*)smem;             // 8 KB
    int*   cnt = (int*)(smem + 8192);      // 512 B (disjoint from lgs)
    if (tid < 128) cnt[tid] = 0;
#pragma unroll
    for (int w = 0; w < NW; ++w) {
        if (w > 0) __syncthreads();
        if (wk == w) {
#pragma unroll
            for (int mi = 0; mi < 2; ++mi)
#pragma unroll
                for (int ni = 0; ni < 4; ++ni)
#pragma unroll
                    for (int gg = 0; gg < 4; ++gg) {
                        int row = 16 * mi + (g4 << 2) + gg;   // C/D: row=(l>>4)*4+reg
                        int e   = 16 * ni + ln15;             // col=l&15
                        float vv = acc[mi][ni][gg] * INV_SCALE2;
                        if (w == 0) lgs[row * 64 + e]  = vv;
                        else        lgs[row * 64 + e] += vv;
                    }
        }
    }
    __syncthreads();

    // ---- per-token top-2 (lane == expert), lower index wins ties ----
#pragma unroll
    for (int t = 0; t < 8; ++t) {
        int rowl = (wk << 3) + t;
        float v = lgs[rowl * 64 + lane];
        float vv = v; int ix = lane;
#pragma unroll
        for (int off = 32; off > 0; off >>= 1) {
            float ov = __shfl_down(vv, off, 64);
            int   oi = __shfl_down(ix, off, 64);
            if (ov > vv || (ov == vv && oi < ix)) { vv = ov; ix = oi; }
        }
        int   i1 = __shfl(ix, 0, 64);
        float v1 = __shfl(vv, 0, 64);

        vv = (lane == i1) ? -3.0e38f : v; ix = lane;
#pragma unroll
        for (int off = 32; off > 0; off >>= 1) {
            float ov = __shfl_down(vv, off, 64);
            int   oi = __shfl_down(ix, off, 64);
            if (ov > vv || (ov == vv && oi < ix)) { vv = ov; ix = oi; }
        }
        int   i2 = __shfl(ix, 0, 64);
        float v2 = __shfl(vv, 0, 64);

        if (lane == 0) {
            int n = t0 + rowl;
            idx0[n] = (unsigned char)i1;
            idx1[n] = (unsigned char)i2;
            dlt[n]  = v2 - v1;             // probs recomputed in k_rank_out
            atomicAdd(&cnt[i1], 1);
            atomicAdd(&cnt[64 + i2], 1);
        }
    }

    __syncthreads();
    if (tid < 128) {
        int e = tid & 63, k = tid >> 6;    // segment s = k*nblk + block (k-major = rank order)
        gcounts[(size_t)e * (2 * nblk) + k * nblk + blockIdx.x] = (unsigned short)cnt[tid];
    }
}

// ---------------- K2: in-place exclusive prefix over segments, per expert ----------------
__launch_bounds__(64)
__global__ void k_scan2(unsigned short* __restrict__ g, int S)
{
    const int e = blockIdx.x, lane = threadIdx.x;
    unsigned short* row = g + (size_t)e * S;
    int vals[16];                          // S = 1024 -> 16 rounds of 64
    const int R = S >> 6;
#pragma unroll
    for (int r = 0; r < 16; ++r) if (r < R) vals[r] = row[(r << 6) + lane];
    int running = 0;
#pragma unroll
    for (int r = 0; r < 16; ++r) {
        if (r >= R) break;
        int v = vals[r], s = v;
#pragma unroll
        for (int off = 1; off < 64; off <<= 1) {
            int t = __shfl_up(s, off, 64);
            if (lane >= off) s += t;
        }
        row[(r << 6) + lane] = (unsigned short)(s - v + running);   // exclusive + carry
        running += __shfl(s, 63, 64);
    }
}

// ---------------- K3: ranks (1 prefix load + ballot) + mask + tail ----------------
__launch_bounds__(128)
__global__ void k_rank_out(const unsigned char* __restrict__ idx0, const unsigned char* __restrict__ idx1,
                           const unsigned short* __restrict__ gpre, const float* __restrict__ dlt,
                           float* __restrict__ out, int N, int cap, int nblk)
{
    const int b = blockIdx.x, tid = threadIdx.x;
    const int lane = tid & 63, kk = tid >> 6;   // wave 0: k=0, wave 1: k=1
    const int t0 = b * BT;
    __shared__ int sm_ix[2][BT], sm_rk[2][BT];

    int v = -1, base = 0;
    if (lane < BT) {
        v = (kk ? idx1 : idx0)[t0 + lane];
        base = gpre[(size_t)v * (2 * nblk) + kk * nblk + b];   // exclusive prefix of earlier segments
    }
    const unsigned long long ltm = (1ull << lane) - 1ull;
    int pre = 0;
    for (int e = 0; e < 64; ++e) {
        unsigned long long bb = __ballot(v == e);
        if (v == e) pre = __popcll(bb & ltm);
    }
    if (lane < BT) { sm_ix[kk][lane] = v; sm_rk[kk][lane] = base + pre; }
    __syncthreads();

    // one-hot capacity mask: 32 tokens x 128 floats = 1024 float4, 8/thread
#pragma unroll
    for (int rep = 0; rep < 8; ++rep) {
        int f   = tid + 128 * rep;
        int n2  = f >> 5;
        int rem = (f & 31) * 4;
        int kq  = rem >> 6;
        int e0  = rem & 63;
        int ix  = sm_ix[kq][n2];
        int rr  = sm_rk[kq][n2];
        float val = (rr < cap) ? 1.0f : 0.0f;
        float4 o = make_float4(0.f, 0.f, 0.f, 0.f);
        int d = ix - e0;
        if (d >= 0 && d < 4) ((float*)&o)[d] = val;
        *(float4*)(out + (size_t)(t0 + n2) * 128 + rem) = o;
    }

    // tail: probs_masked / indices / final_rank / capacity
    size_t B = (size_t)2 * N * E_DIM;
    if (tid < 2 * BT) {
        int n2 = tid >> 1, kq = tid & 1;
        int n  = t0 + n2;
        int gi = 2 * n + kq;
        int ix = sm_ix[kq][n2];
        int rr = sm_rk[kq][n2];
        float d  = dlt[n];                  // v2 - v1 (<= 0)
        float e1 = expf(d);
        float inv = 1.0f / (1.0f + e1);     // = jax f32 softmax([v1,v2])
        float p  = kq ? (e1 * inv) : inv;
        bool keep = rr < cap;
        out[B + gi]         = keep ? p : 0.0f;
        out[B + 2 * N + gi] = (float)ix;
        out[B + 4 * N + gi] = (float)rr;
    }
    if (b == 0 && tid == 0) out[B + 6 * N] = (float)cap;
}

extern "C" void kernel_launch(void* const* d_in, const int* in_sizes, int n_in,
                              void* d_out, int out_size, void* d_ws, size_t ws_size,
                              hipStream_t stream)
{
    const float* x  = (const float*)d_in[0];
    const float* wg = (const float*)d_in[1];
    const int N = in_sizes[0] / C_DIM;   // 16384 tokens
    const int nblk = N / BT;             // 512

    // workspace: idx0[N]u8 idx1[N]u8 dlt[N]f32 gcounts[64][2*nblk]u16 wfrag[256K f16] = 736 KB
    char* ws = (char*)d_ws;
    unsigned char*  idx0    = (unsigned char*)ws;
    unsigned char*  idx1    = idx0 + N;
    float*          dlt     = (float*)(idx1 + N);
    unsigned short* gcounts = (unsigned short*)(dlt + N);
    _Float16*       wfrag   = (_Float16*)(gcounts + (size_t)64 * 2 * nblk);

    float* out = (float*)d_out;

    int cap = (int)((long long)2 * 2 * N / E_DIM);   // TOP_K * EVAL_CAPACITY * N / E
    if (cap < 4) cap = 4;

    k_wsplit<<<64, 256, 0, stream>>>(wg, wfrag);
    k_logits_top2<<<nblk, 256, 0, stream>>>(x, wfrag, idx0, idx1, dlt, gcounts, nblk);
    k_scan2<<<E_DIM, 64, 0, stream>>>(gcounts, 2 * nblk);
    k_rank_out<<<nblk, 128, 0, stream>>>(idx0, idx1, gcounts, dlt, out, N, cap, nblk);
}

// Round 8
// 234.543 us; speedup vs baseline: 1.0818x; 1.0133x over previous
//
#include <hip/hip_runtime.h>
#include <math.h>

#define C_DIM 2048
#define E_DIM 64
#define BT    32       // tokens per block
#define NW    4        // waves per block = K-split factor

typedef _Float16 v8hf  __attribute__((ext_vector_type(8)));
typedef float    f32x4 __attribute__((ext_vector_type(4)));

#define SCALE      64.0f
#define INV_SCALE2 (1.0f/4096.0f)

typedef __attribute__((address_space(3))) char lds_char;

__device__ __forceinline__ void gl16(const void* g, lds_char* l)
{
    __builtin_amdgcn_global_load_lds((const __attribute__((address_space(1))) void*)g,
                                     (__attribute__((address_space(3))) void*)l, 16, 0, 0);
}

// ---------------- K0: w -> fragment-ordered f16 (hi,lo), scaled x64 ----------------
// For K32-step q (0..63), expert-group ni (0..3): 2 KB block = hi(1 KB) + lo(1 KB),
// each 64 lanes x 16 B. Lane l holds w[16ni+(l&15)][32q+(l>>4)*8 .. +8].
__launch_bounds__(256)
__global__ void k_wsplit(const float* __restrict__ w, _Float16* __restrict__ wfrag)
{
    int t  = blockIdx.x * 256 + threadIdx.x;   // 0..16383
    int l  = t & 63;
    int ni = (t >> 6) & 3;
    int q  = t >> 8;
    int e  = 16 * ni + (l & 15);
    int k0 = 32 * q + (l >> 4) * 8;
    const float* src = w + (size_t)e * C_DIM + k0;
    float4 a = *(const float4*)(src);
    float4 b = *(const float4*)(src + 4);
    float s[8] = {a.x, a.y, a.z, a.w, b.x, b.y, b.z, b.w};
    v8hf hv, lv;
#pragma unroll
    for (int j = 0; j < 8; ++j) {
        float sc = s[j] * SCALE;
        _Float16 h = (_Float16)sc;          // RNE
        hv[j] = h;
        lv[j] = (_Float16)(sc - (float)h);  // Sterbenz-exact residual, then RNE
    }
    size_t fo = (size_t)(q * 4 + ni) * 1024;   // f16 units: 1024 f16 = 2 KB per (q,ni)
    *(v8hf*)(wfrag + fo + l * 8)       = hv;
    *(v8hf*)(wfrag + fo + 512 + l * 8) = lv;
}

// ---------------- K1: deep-async MFMA logits + top-2 + histogram ----------------
// Block: 32 tokens x 64 experts, 4 waves = 4-way K-split (wave wk owns K32-step
// q = 4c+wk of chunk c). x flows HBM -> LDS via global_load_lds into a 4-deep
// per-wave ring of fragment-plane slices (lane-linear dest == A-frag order;
// per-lane scatter on the GLOBAL side). FIFO DISCIPLINE (the R7 fix): B(c) is
// issued BEFORE X(c+1), so the wait for B(c)'s registers retires only {B(c),X(c)}
// and leaves X(c+1),X(c+2) permanently in flight (true depth-2 pipeline,
// 64 KB/CU outstanding). Per chunk: wait vmcnt(16) -> compute -> issue B(c+2)
// into the freed slot -> issue X(c+3). ZERO barriers in the K-loop.
// f32->f16 hi/lo split on the LDS-read side; 3 MFMA products into one fp32 acc.
__launch_bounds__(256, 2)
__global__ void k_logits_top2(const float* __restrict__ x, const _Float16* __restrict__ wfrag,
                              unsigned char* __restrict__ idx0, unsigned char* __restrict__ idx1,
                              float* __restrict__ dlt, unsigned short* __restrict__ gcounts,
                              int nblk)
{
    __shared__ alignas(16) char smem[65536];   // ring: [slot 0..3][wave][mi][plane] 1 KB planes

    const int tid  = threadIdx.x;
    const int lane = tid & 63;
    const int wk   = tid >> 6;            // 0..3 : K-split index
    const int ln15 = lane & 15;
    const int g4   = lane >> 4;
    const int t0   = blockIdx.x * BT;

    f32x4 acc[2][4];
#pragma unroll
    for (int mi = 0; mi < 2; ++mi)
#pragma unroll
        for (int ni = 0; ni < 4; ++ni) acc[mi][ni] = (f32x4)0.0f;

    v8hf bh[2][4], bl[2][4];              // B double-buffer (literal indices only)
    v8hf ah[2], al[2];

    // per-lane global base for A-fragments: row t0+ln15, k-offset 32wk + 8*g4
    const float* xlane = x + (size_t)(t0 + ln15) * C_DIM + 32 * wk + 8 * g4;
    const char*  wlane = (const char*)wfrag + (lane << 4);
    lds_char* s3    = (lds_char*)smem;
    lds_char* sbase = s3 + wk * 4096;     // + (c&3)*16384 + mi*2048 + p*1024

#define ISSUE_X(cc)                                                             \
    do {                                                                        \
        lds_char*    d  = sbase + (((cc) & 3) * 16384);                         \
        const float* gp = xlane + (cc) * 128;                                   \
        gl16(gp,                  d);                                           \
        gl16(gp + 4,              d + 1024);                                    \
        gl16(gp + 16 * C_DIM,     d + 2048);                                    \
        gl16(gp + 16 * C_DIM + 4, d + 3072);                                    \
    } while (0)

#define ISSUE_B(cc, s)                                                          \
    do {                                                                        \
        const char* wp = wlane + ((size_t)(4 * (cc) + wk) << 13);               \
        bh[s][0] = *(const v8hf*)(wp);          bl[s][0] = *(const v8hf*)(wp + 1024); \
        bh[s][1] = *(const v8hf*)(wp + 2048);   bl[s][1] = *(const v8hf*)(wp + 3072); \
        bh[s][2] = *(const v8hf*)(wp + 4096);   bl[s][2] = *(const v8hf*)(wp + 5120); \
        bh[s][3] = *(const v8hf*)(wp + 6144);   bl[s][3] = *(const v8hf*)(wp + 7168); \
    } while (0)

#define CVT(mi, lo, hi)                                                         \
    do {                                                                        \
        _Pragma("unroll")                                                       \
        for (int j = 0; j < 4; ++j) {                                           \
            float sc0 = (lo)[j] * SCALE;                                        \
            _Float16 h0 = (_Float16)sc0;                                        \
            ah[mi][j] = h0; al[mi][j] = (_Float16)(sc0 - (float)h0);            \
            float sc1 = (hi)[j] * SCALE;                                        \
            _Float16 h1 = (_Float16)sc1;                                        \
            ah[mi][j + 4] = h1; al[mi][j + 4] = (_Float16)(sc1 - (float)h1);    \
        }                                                                       \
    } while (0)

#define COMPUTE(cc, s)                                                          \
    do {                                                                        \
        const char* rb = smem + wk * 4096 + (((cc) & 3) * 16384) + lane * 16;   \
        f32x4 lo0 = *(const f32x4*)(rb);                                        \
        f32x4 hi0 = *(const f32x4*)(rb + 1024);                                 \
        f32x4 lo1 = *(const f32x4*)(rb + 2048);                                 \
        f32x4 hi1 = *(const f32x4*)(rb + 3072);                                 \
        CVT(0, lo0, hi0);                                                       \
        CVT(1, lo1, hi1);                                                       \
        _Pragma("unroll")                                                       \
        for (int ni = 0; ni < 4; ++ni) {                                        \
            acc[0][ni] = __builtin_amdgcn_mfma_f32_16x16x32_f16(ah[0], bh[s][ni], acc[0][ni], 0, 0, 0); \
            acc[0][ni] = __builtin_amdgcn_mfma_f32_16x16x32_f16(ah[0], bl[s][ni], acc[0][ni], 0, 0, 0); \
            acc[0][ni] = __builtin_amdgcn_mfma_f32_16x16x32_f16(al[0], bh[s][ni], acc[0][ni], 0, 0, 0); \
            acc[1][ni] = __builtin_amdgcn_mfma_f32_16x16x32_f16(ah[1], bh[s][ni], acc[1][ni], 0, 0, 0); \
            acc[1][ni] = __builtin_amdgcn_mfma_f32_16x16x32_f16(ah[1], bl[s][ni], acc[1][ni], 0, 0, 0); \
            acc[1][ni] = __builtin_amdgcn_mfma_f32_16x16x32_f16(al[1], bh[s][ni], acc[1][ni], 0, 0, 0); \
        }                                                                       \
    } while (0)

// steady-state FIFO (oldest->newest) before the wait at chunk c:
//   X(c)4, B(c)8, X(c+1)4, B(c+1)8, X(c+2)4  = 28 outstanding.
// vmcnt(16) retires exactly the oldest 12 = {X(c), B(c)} -> compute(c) has both
// its LDS planes and its B registers; X(c+1), X(c+2) stay in flight (depth 2).
// Issues go AFTER compute: B(c+2) reuses the register slot compute(c) just
// drained (in-order issue makes the WAR safe); X(c+3) reuses the LDS slot
// compute(c-1) finished. Wrap-issued tails keep the count uniform (redundant
// same-byte reloads of early chunks, harmless).
#define CHUNK(c, S)                                                             \
    asm volatile("s_waitcnt vmcnt(16)" ::: "memory");                           \
    COMPUTE(c, S);                                                              \
    ISSUE_B(((c) + 2) & 15, S);                                                 \
    ISSUE_X(((c) + 3) & 15);

    // prologue: B(0), X(0), X(1), B(1), X(2)  (every B(c) older than X(c+1))
    ISSUE_B(0, 0);
    ISSUE_X(0); ISSUE_X(1);
    ISSUE_B(1, 1);
    ISSUE_X(2);

    CHUNK(0, 0)  CHUNK(1, 1)  CHUNK(2, 0)  CHUNK(3, 1)
    CHUNK(4, 0)  CHUNK(5, 1)  CHUNK(6, 0)  CHUNK(7, 1)
    CHUNK(8, 0)  CHUNK(9, 1)  CHUNK(10, 0) CHUNK(11, 1)
    CHUNK(12, 0) CHUNK(13, 1) CHUNK(14, 0) CHUNK(15, 1)

    asm volatile("s_waitcnt vmcnt(0)" ::: "memory");
    __syncthreads();                       // ring dead; smem reused below

    // ---- deterministic K-split reduction into lgs[32][64] ----
    float* lgs = (float*)smem;             // 8 KB
    int*   cnt = (int*)(smem + 8192);      // 512 B (disjoint from lgs)
    if (tid < 128) cnt[tid] = 0;
#pragma unroll
    for (int w = 0; w < NW; ++w) {
        if (w > 0) __syncthreads();
        if (wk == w) {
#pragma unroll
            for (int mi = 0; mi < 2; ++mi)
#pragma unroll
                for (int ni = 0; ni < 4; ++ni)
#pragma unroll
                    for (int gg = 0; gg < 4; ++gg) {
                        int row = 16 * mi + (g4 << 2) + gg;   // C/D: row=(l>>4)*4+reg
                        int e   = 16 * ni + ln15;             // col=l&15
                        float vv = acc[mi][ni][gg] * INV_SCALE2;
                        if (w == 0) lgs[row * 64 + e]  = vv;
                        else        lgs[row * 64 + e] += vv;
                    }
        }
    }
    __syncthreads();

    // ---- per-token top-2 (lane == expert), lower index wins ties ----
#pragma unroll
    for (int t = 0; t < 8; ++t) {
        int rowl = (wk << 3) + t;
        float v = lgs[rowl * 64 + lane];
        float vv = v; int ix = lane;
#pragma unroll
        for (int off = 32; off > 0; off >>= 1) {
            float ov = __shfl_down(vv, off, 64);
            int   oi = __shfl_down(ix, off, 64);
            if (ov > vv || (ov == vv && oi < ix)) { vv = ov; ix = oi; }
        }
        int   i1 = __shfl(ix, 0, 64);
        float v1 = __shfl(vv, 0, 64);

        vv = (lane == i1) ? -3.0e38f : v; ix = lane;
#pragma unroll
        for (int off = 32; off > 0; off >>= 1) {
            float ov = __shfl_down(vv, off, 64);
            int   oi = __shfl_down(ix, off, 64);
            if (ov > vv || (ov == vv && oi < ix)) { vv = ov; ix = oi; }
        }
        int   i2 = __shfl(ix, 0, 64);
        float v2 = __shfl(vv, 0, 64);

        if (lane == 0) {
            int n = t0 + rowl;
            idx0[n] = (unsigned char)i1;
            idx1[n] = (unsigned char)i2;
            dlt[n]  = v2 - v1;             // probs recomputed in k_rank_out
            atomicAdd(&cnt[i1], 1);
            atomicAdd(&cnt[64 + i2], 1);
        }
    }

    __syncthreads();
    if (tid < 128) {
        int e = tid & 63, k = tid >> 6;    // segment s = k*nblk + block (k-major = rank order)
        gcounts[(size_t)e * (2 * nblk) + k * nblk + blockIdx.x] = (unsigned short)cnt[tid];
    }
}

// ---------------- K2: in-place exclusive prefix over segments, per expert ----------------
__launch_bounds__(64)
__global__ void k_scan2(unsigned short* __restrict__ g, int S)
{
    const int e = blockIdx.x, lane = threadIdx.x;
    unsigned short* row = g + (size_t)e * S;
    int vals[16];                          // S = 1024 -> 16 rounds of 64
    const int R = S >> 6;
#pragma unroll
    for (int r = 0; r < 16; ++r) if (r < R) vals[r] = row[(r << 6) + lane];
    int running = 0;
#pragma unroll
    for (int r = 0; r < 16; ++r) {
        if (r >= R) break;
        int v = vals[r], s = v;
#pragma unroll
        for (int off = 1; off < 64; off <<= 1) {
            int t = __shfl_up(s, off, 64);
            if (lane >= off) s += t;
        }
        row[(r << 6) + lane] = (unsigned short)(s - v + running);   // exclusive + carry
        running += __shfl(s, 63, 64);
    }
}

// ---------------- K3: ranks (1 prefix load + ballot) + mask + tail ----------------
__launch_bounds__(128)
__global__ void k_rank_out(const unsigned char* __restrict__ idx0, const unsigned char* __restrict__ idx1,
                           const unsigned short* __restrict__ gpre, const float* __restrict__ dlt,
                           float* __restrict__ out, int N, int cap, int nblk)
{
    const int b = blockIdx.x, tid = threadIdx.x;
    const int lane = tid & 63, kk = tid >> 6;   // wave 0: k=0, wave 1: k=1
    const int t0 = b * BT;
    __shared__ int sm_ix[2][BT], sm_rk[2][BT];

    int v = -1, base = 0;
    if (lane < BT) {
        v = (kk ? idx1 : idx0)[t0 + lane];
        base = gpre[(size_t)v * (2 * nblk) + kk * nblk + b];   // exclusive prefix of earlier segments
    }
    const unsigned long long ltm = (1ull << lane) - 1ull;
    int pre = 0;
    for (int e = 0; e < 64; ++e) {
        unsigned long long bb = __ballot(v == e);
        if (v == e) pre = __popcll(bb & ltm);
    }
    if (lane < BT) { sm_ix[kk][lane] = v; sm_rk[kk][lane] = base + pre; }
    __syncthreads();

    // one-hot capacity mask: 32 tokens x 128 floats = 1024 float4, 8/thread
#pragma unroll
    for (int rep = 0; rep < 8; ++rep) {
        int f   = tid + 128 * rep;
        int n2  = f >> 5;
        int rem = (f & 31) * 4;
        int kq  = rem >> 6;
        int e0  = rem & 63;
        int ix  = sm_ix[kq][n2];
        int rr  = sm_rk[kq][n2];
        float val = (rr < cap) ? 1.0f : 0.0f;
        float4 o = make_float4(0.f, 0.f, 0.f, 0.f);
        int d = ix - e0;
        if (d >= 0 && d < 4) ((float*)&o)[d] = val;
        *(float4*)(out + (size_t)(t0 + n2) * 128 + rem) = o;
    }

    // tail: probs_masked / indices / final_rank / capacity
    size_t B = (size_t)2 * N * E_DIM;
    if (tid < 2 * BT) {
        int n2 = tid >> 1, kq = tid & 1;
        int n  = t0 + n2;
        int gi = 2 * n + kq;
        int ix = sm_ix[kq][n2];
        int rr = sm_rk[kq][n2];
        float d  = dlt[n];                  // v2 - v1 (<= 0)
        float e1 = expf(d);
        float inv = 1.0f / (1.0f + e1);     // = jax f32 softmax([v1,v2])
        float p  = kq ? (e1 * inv) : inv;
        bool keep = rr < cap;
        out[B + gi]         = keep ? p : 0.0f;
        out[B + 2 * N + gi] = (float)ix;
        out[B + 4 * N + gi] = (float)rr;
    }
    if (b == 0 && tid == 0) out[B + 6 * N] = (float)cap;
}

extern "C" void kernel_launch(void* const* d_in, const int* in_sizes, int n_in,
                              void* d_out, int out_size, void* d_ws, size_t ws_size,
                              hipStream_t stream)
{
    const float* x  = (const float*)d_in[0];
    const float* wg = (const float*)d_in[1];
    const int N = in_sizes[0] / C_DIM;   // 16384 tokens
    const int nblk = N / BT;             // 512

    // workspace: idx0[N]u8 idx1[N]u8 dlt[N]f32 gcounts[64][2*nblk]u16 wfrag[256K f16] = 736 KB
    char* ws = (char*)d_ws;
    unsigned char*  idx0    = (unsigned char*)ws;
    unsigned char*  idx1    = idx0 + N;
    float*          dlt     = (float*)(idx1 + N);
    unsigned short* gcounts = (unsigned short*)(dlt + N);
    _Float16*       wfrag   = (_Float16*)(gcounts + (size_t)64 * 2 * nblk);

    float* out = (float*)d_out;

    int cap = (int)((long long)2 * 2 * N / E_DIM);   // TOP_K * EVAL_CAPACITY * N / E
    if (cap < 4) cap = 4;

    k_wsplit<<<64, 256, 0, stream>>>(wg, wfrag);
    k_logits_top2<<<nblk, 256, 0, stream>>>(x, wfrag, idx0, idx1, dlt, gcounts, nblk);
    k_scan2<<<E_DIM, 64, 0, stream>>>(gcounts, 2 * nblk);
    k_rank_out<<<nblk, 128, 0, stream>>>(idx0, idx1, gcounts, dlt, out, N, cap, nblk);
}